// Round 6
// baseline (407.168 us; speedup 1.0000x reference)
//
#include <hip/hip_runtime.h>

#define N_NODES  100000
#define N_EDGES  2000000
#define N_GRAPHS 1000
#define NFEAT    7
#define BN_EPS   1e-5f
#define MAXDEG   64    // in-degree ~ Poisson(20); P(max over 100k > 63) < 1e-9

#define BSH      7     // 128-node dst buckets
#define NBKT     782   // ceil(100000/128)
#define BCAP     3584  // per-bucket edge cap: mean 2560 + 20 sigma
#define E_PER_BLK 4096

// bf16 helpers (storage only; all arithmetic fp32)
__device__ __forceinline__ unsigned bf16_rne(float f) {
  unsigned u = __float_as_uint(f);
  return (u + 0x7FFFu + ((u >> 16) & 1u)) >> 16;
}
__device__ __forceinline__ float bf_lo(unsigned u) { return __uint_as_float(u << 16); }
__device__ __forceinline__ float bf_hi(unsigned u) { return __uint_as_float(u & 0xFFFF0000u); }

// ---- VALU cross-lane helpers (replace ds_bpermute-based __shfl) ----
// DPP move: result = x[dpp-mapped lane]; ctrl must be compile-time constant.
template <int CTRL>
__device__ __forceinline__ float dppmov(float x) {
  return __uint_as_float((unsigned)__builtin_amdgcn_update_dpp(
      (int)__float_as_uint(x), (int)__float_as_uint(x), CTRL, 0xf, 0xf, false));
}
#define DPP_XOR1  0xB1   // quad_perm [1,0,3,2]
#define DPP_XOR2  0x4E   // quad_perm [2,3,0,1]
#define DPP_ROR8  0x128  // row_ror:8 == xor8 within 16-lane row
#define DPP_HI    0xF5   // quad_perm [1,1,3,3] -> lane gets value from lane|1

// x + x[lane^32] via v_permlane32_swap_b32 (gfx950): with both inputs = x,
// result pair is r0[lane] = x[lane|32], r1[lane] = x[lane&31].
__device__ __forceinline__ float sumxor32(float x) {
  auto r = __builtin_amdgcn_permlane32_swap(__float_as_uint(x), __float_as_uint(x),
                                            false, false);
  return __uint_as_float(r[0]) + __uint_as_float(r[1]);
}

// ---------------- b1: bucket edges by dst>>7, block-contiguous writes ----------------
__global__ __launch_bounds__(1024) void b1_bucket(const int* __restrict__ src,
                                                  const int* __restrict__ dst,
                                                  int* __restrict__ gCur,
                                                  unsigned* __restrict__ ebuf) {
  __shared__ int hist[NBKT], base[NBKT];
  int tid = threadIdx.x;
  for (int i = tid; i < NBKT; i += 1024) hist[i] = 0;
  __syncthreads();
  unsigned pk[4];
  int bo[4];
  int e0 = blockIdx.x * E_PER_BLK;
#pragma unroll
  for (int k = 0; k < 4; ++k) {
    int e = e0 + k * 1024 + tid;
    if (e < N_EDGES) {
      int d = dst[e], s = src[e];
      int b = d >> BSH;
      int off = atomicAdd(&hist[b], 1);
      pk[k] = ((unsigned)(d & 127) << 17) | (unsigned)s;
      bo[k] = (b << 17) | off;
    } else {
      bo[k] = -1;
    }
  }
  __syncthreads();
  for (int i = tid; i < NBKT; i += 1024)
    base[i] = hist[i] ? atomicAdd(&gCur[i], hist[i]) : 0;
  __syncthreads();
#pragma unroll
  for (int k = 0; k < 4; ++k) {
    if (bo[k] >= 0) {
      int b = bo[k] >> 17, off = bo[k] & 0x1FFFF;
      int p = base[b] + off;
      if (p < BCAP) ebuf[(size_t)b * BCAP + p] = pk[k];
    }
  }
}

// ---------------- b2: one block per bucket -> padded csr + cnt ----------------
__global__ __launch_bounds__(512) void b2_csr(const unsigned* __restrict__ ebuf,
                                              const int* __restrict__ gCnt,
                                              int* __restrict__ cnt,
                                              int* __restrict__ csr) {
  __shared__ int hist[128];
  __shared__ int stage[128 * MAXDEG];
  int b = blockIdx.x, tid = threadIdx.x;
  if (tid < 128) hist[tid] = 0;
  __syncthreads();
  int n = gCnt[b];
  if (n > BCAP) n = BCAP;
  const unsigned* eb = ebuf + (size_t)b * BCAP;
  for (int i = tid; i < n; i += 512) {
    unsigned pk = eb[i];
    int dloc = (int)(pk >> 17);
    int slot = atomicAdd(&hist[dloc], 1);
    if (slot < MAXDEG) stage[(dloc << 6) + slot] = (int)(pk & 0x1FFFFu);
  }
  __syncthreads();
  if (tid < 128) {
    int gnode = (b << BSH) + tid;
    if (gnode < N_NODES) cnt[gnode] = hist[tid];
  }
  const int4* st4 = (const int4*)stage;
  int4* dst4 = (int4*)(csr + (size_t)b * (128 * MAXDEG));
  for (int i = tid; i < 128 * MAXDEG / 4; i += 512) dst4[i] = st4[i];
}

// ---------------- xcvt: x (fp32 [N,7]) -> xc (bf16 [N,8], pad dim7 = 0) ----------------
__global__ __launch_bounds__(256) void xcvt_kernel(const float* __restrict__ x,
                                                   unsigned* __restrict__ xc) {
  int i = blockIdx.x * 256 + threadIdx.x;
  if (i >= N_NODES * 4) return;
  int n = i >> 2, p = i & 3;
  float lo = x[n * 7 + 2 * p];
  float hi = (2 * p + 1 < 7) ? x[n * 7 + 2 * p + 1] : 0.f;
  xc[i] = bf16_rne(lo) | (bf16_rne(hi) << 16);
}

// ---------------- conv1: node-PAIR cooperative-row gather (proven R2) ----------------
__global__ __launch_bounds__(256) void gin1(
    const unsigned short* __restrict__ xc16, const int* __restrict__ cnt,
    const int* __restrict__ csr,
    const float* __restrict__ W1, const float* __restrict__ b1,
    const float* __restrict__ W2, const float* __restrict__ b2,
    const float* __restrict__ gamma, const float* __restrict__ beta,
    const float* __restrict__ mean, const float* __restrict__ var,
    unsigned short* __restrict__ hout16) {
  __shared__ __align__(16) float zsA[4][8], zsB[4][8];
  __shared__ __align__(16) float tsA[4][32], tsB[4][32];
  int tid = threadIdx.x;
  int w = __builtin_amdgcn_readfirstlane(tid >> 6);
  int lane = tid & 63;
  int grp = lane >> 2;   // row group (16 rows per gather step)
  int ch  = lane & 3;    // 4-byte chunk = dims [2ch, 2ch+1]
  int half = lane >> 5, j = lane & 31;  // MLP roles

  float wr1[4], wr2[16];
#pragma unroll
  for (int i = 0; i < 4; ++i) {
    int k = half * 4 + i;
    wr1[i] = (k < 7) ? W1[k * 32 + j] : 0.f;
  }
#pragma unroll
  for (int i = 0; i < 16; ++i) wr2[i] = W2[(half * 16 + i) * 32 + j];
  float vb1 = b1[j], vb2 = b2[j];
  float sc = gamma[j] * rsqrtf(var[j] + BN_EPS);
  float sh = beta[j] - mean[j] * sc;

  const unsigned* xc32 = (const unsigned*)xc16;  // 4 x unsigned per 16-B row

  const int NW = gridDim.x * 4;
  const int NPAIR = N_NODES / 2;
  for (int pr = blockIdx.x * 4 + w; pr < NPAIR; pr += NW) {
    int n0 = 2 * pr, n1 = n0 + 1;
    int d0 = cnt[n0];
    int d1 = cnt[n1];
    if (d0 > 63) d0 = 63;
    if (d1 > 63) d1 = 63;
    int dE0 = d0 + 1, dE1 = d1 + 1;

    int idx0 = (lane < d0) ? csr[n0 * MAXDEG + lane] : n0;
    int idx1 = (lane < d1) ? csr[n1 * MAXDEG + lane] : n1;

    unsigned vA[4], vB[4];
#pragma unroll
    for (int s = 0; s < 4; ++s) {
      int sidA = __shfl(idx0, s * 16 + grp);
      vA[s] = xc32[(size_t)sidA * 4 + ch];
    }
#pragma unroll
    for (int s = 0; s < 4; ++s) {
      int sidB = __shfl(idx1, s * 16 + grp);
      vB[s] = xc32[(size_t)sidB * 4 + ch];
    }

    float a0 = 0.f, a1 = 0.f;   // node0
    float c0 = 0.f, c1 = 0.f;   // node1
#pragma unroll
    for (int s = 0; s < 4; ++s) {
      int e = s * 16 + grp;
      if (e < dE0) { a0 += bf_lo(vA[s]); a1 += bf_hi(vA[s]); }
      if (e < dE1) { c0 += bf_lo(vB[s]); c1 += bf_hi(vB[s]); }
    }
#pragma unroll
    for (int m = 4; m <= 32; m <<= 1) {
      a0 += __shfl_xor(a0, m); a1 += __shfl_xor(a1, m);
      c0 += __shfl_xor(c0, m); c1 += __shfl_xor(c1, m);
    }
    if (grp == 0) {  // lanes 0..3 deposit dims [2ch, 2ch+1]
      float2 za = {a0, a1};
      float2 zc = {c0, c1};
      *(float2*)&zsA[w][ch * 2] = za;
      *(float2*)&zsB[w][ch * 2] = zc;
    }

    // ---- MLP node0 ----
    float tp = half ? 0.f : vb1;
    {
      const float4* zp = (const float4*)&zsA[w][half * 4];
      float4 z0 = zp[0];
      tp = fmaf(z0.x, wr1[0], tp); tp = fmaf(z0.y, wr1[1], tp);
      tp = fmaf(z0.z, wr1[2], tp); tp = fmaf(z0.w, wr1[3], tp);
    }
    tp += __shfl_xor(tp, 32);
    tp = fmaxf(tp, 0.f);
    if (!half) tsA[w][j] = tp;

    float op = half ? 0.f : vb2;
    {
      const float4* tpp = (const float4*)&tsA[w][half * 16];
      float4 t0 = tpp[0], t1 = tpp[1], t2 = tpp[2], t3 = tpp[3];
      op = fmaf(t0.x, wr2[0], op);  op = fmaf(t0.y, wr2[1], op);
      op = fmaf(t0.z, wr2[2], op);  op = fmaf(t0.w, wr2[3], op);
      op = fmaf(t1.x, wr2[4], op);  op = fmaf(t1.y, wr2[5], op);
      op = fmaf(t1.z, wr2[6], op);  op = fmaf(t1.w, wr2[7], op);
      op = fmaf(t2.x, wr2[8], op);  op = fmaf(t2.y, wr2[9], op);
      op = fmaf(t2.z, wr2[10], op); op = fmaf(t2.w, wr2[11], op);
      op = fmaf(t3.x, wr2[12], op); op = fmaf(t3.y, wr2[13], op);
      op = fmaf(t3.z, wr2[14], op); op = fmaf(t3.w, wr2[15], op);
    }
    op += __shfl_xor(op, 32);
    if (!half) {
      op = fmaxf(op, 0.f) * sc + sh;
      float hi = __shfl(op, j | 1);
      if ((j & 1) == 0) {
        unsigned pk = bf16_rne(op) | (bf16_rne(hi) << 16);
        ((unsigned*)hout16)[n0 * 16 + (j >> 1)] = pk;
      }
    }

    // ---- MLP node1 ----
    float tq = half ? 0.f : vb1;
    {
      const float4* zp = (const float4*)&zsB[w][half * 4];
      float4 z0 = zp[0];
      tq = fmaf(z0.x, wr1[0], tq); tq = fmaf(z0.y, wr1[1], tq);
      tq = fmaf(z0.z, wr1[2], tq); tq = fmaf(z0.w, wr1[3], tq);
    }
    tq += __shfl_xor(tq, 32);
    tq = fmaxf(tq, 0.f);
    if (!half) tsB[w][j] = tq;

    float oq = half ? 0.f : vb2;
    {
      const float4* tpp = (const float4*)&tsB[w][half * 16];
      float4 t0 = tpp[0], t1 = tpp[1], t2 = tpp[2], t3 = tpp[3];
      oq = fmaf(t0.x, wr2[0], oq);  oq = fmaf(t0.y, wr2[1], oq);
      oq = fmaf(t0.z, wr2[2], oq);  oq = fmaf(t0.w, wr2[3], oq);
      oq = fmaf(t1.x, wr2[4], oq);  oq = fmaf(t1.y, wr2[5], oq);
      oq = fmaf(t1.z, wr2[6], oq);  oq = fmaf(t1.w, wr2[7], oq);
      oq = fmaf(t2.x, wr2[8], oq);  oq = fmaf(t2.y, wr2[9], oq);
      oq = fmaf(t2.z, wr2[10], oq); oq = fmaf(t2.w, wr2[11], oq);
      oq = fmaf(t3.x, wr2[12], oq); oq = fmaf(t3.y, wr2[13], oq);
      oq = fmaf(t3.z, wr2[14], oq); oq = fmaf(t3.w, wr2[15], oq);
    }
    oq += __shfl_xor(oq, 32);
    if (!half) {
      oq = fmaxf(oq, 0.f) * sc + sh;
      float hi = __shfl(oq, j | 1);
      if ((j & 1) == 0) {
        unsigned pk = bf16_rne(oq) | (bf16_rne(hi) << 16);
        ((unsigned*)hout16)[n1 * 16 + (j >> 1)] = pk;
      }
    }
  }
}

// ---------------- conv2..5: pair gather, LDS-pipe-minimized (R4/R5) ----------------
// Lane remap: chunk ch = lane bits {2,4} (16 B of the 64-B row), slot-in-step =
// bits {0,1,3,5}. Reduction over slots is ALL-VALU: xor1/xor2 (quad_perm DPP),
// xor8 (row_ror:8 DPP), xor32 (v_permlane32_swap). Idx comes from direct
// per-slot csr loads (VMEM, L1-served) instead of ds_bpermute shfls.
__global__ __launch_bounds__(256) void gin_layer32(
    const unsigned short* __restrict__ hin16, const int* __restrict__ cnt,
    const int* __restrict__ csr,
    const float* __restrict__ W1, const float* __restrict__ b1,
    const float* __restrict__ W2, const float* __restrict__ b2,
    const float* __restrict__ gamma, const float* __restrict__ beta,
    const float* __restrict__ mean, const float* __restrict__ var,
    unsigned short* __restrict__ hout16) {
  __shared__ __align__(16) float zsA[4][32], tsA[4][32];
  __shared__ __align__(16) float zsB[4][32], tsB[4][32];
  int tid = threadIdx.x;
  int w = __builtin_amdgcn_readfirstlane(tid >> 6);  // wave id, force-scalar
  int lane = tid & 63;
  int sl = (lane & 3) | ((lane >> 1) & 4) | ((lane >> 2) & 8);  // bits 0,1,3,5
  int ch = ((lane >> 2) & 1) | ((lane >> 3) & 2);               // bits 2,4
  int half = lane >> 5, j = lane & 31;  // MLP roles

  float wr1[16], wr2[16];
#pragma unroll
  for (int i = 0; i < 16; ++i) wr1[i] = W1[(half * 16 + i) * 32 + j];
#pragma unroll
  for (int i = 0; i < 16; ++i) wr2[i] = W2[(half * 16 + i) * 32 + j];
  float vb1 = b1[j], vb2 = b2[j];
  float sc = gamma[j] * rsqrtf(var[j] + BN_EPS);
  float sh = beta[j] - mean[j] * sc;

  const int NW = gridDim.x * 4;
  const int NPAIR = N_NODES / 2;  // 50000
  for (int pr = blockIdx.x * 4 + w; pr < NPAIR; pr += NW) {
    int n0 = 2 * pr, n1 = n0 + 1;
    int d0 = cnt[n0];
    int d1 = cnt[n1];
    if (d0 > 63) d0 = 63;
    if (d1 > 63) d1 = 63;
    int dE0 = d0 + 1, dE1 = d1 + 1;  // + self rows

    float a0 = 0.f, a1 = 0.f, a2 = 0.f, a3 = 0.f;
    float a4 = 0.f, a5 = 0.f, a6 = 0.f, a7 = 0.f;
    float c0 = 0.f, c1 = 0.f, c2 = 0.f, c3 = 0.f;
    float c4 = 0.f, c5 = 0.f, c6 = 0.f, c7 = 0.f;
#pragma unroll
    for (int s = 0; s < 4; ++s) {
      int e = s * 16 + sl;           // slot 0..63
      int i0 = csr[n0 * MAXDEG + e]; // VMEM load, L1-served (64-B window)
      int i1 = csr[n1 * MAXDEG + e];
      int sidA = (e < d0) ? i0 : n0; // pad slots -> self row (valid addr)
      int sidB = (e < d1) ? i1 : n1;
      uint4 vA = *(const uint4*)(hin16 + (size_t)sidA * 32 + ch * 8);
      uint4 vB = *(const uint4*)(hin16 + (size_t)sidB * 32 + ch * 8);
      if (e < dE0) {
        a0 += bf_lo(vA.x); a1 += bf_hi(vA.x);
        a2 += bf_lo(vA.y); a3 += bf_hi(vA.y);
        a4 += bf_lo(vA.z); a5 += bf_hi(vA.z);
        a6 += bf_lo(vA.w); a7 += bf_hi(vA.w);
      }
      if (e < dE1) {
        c0 += bf_lo(vB.x); c1 += bf_hi(vB.x);
        c2 += bf_lo(vB.y); c3 += bf_hi(vB.y);
        c4 += bf_lo(vB.z); c5 += bf_hi(vB.z);
        c6 += bf_lo(vB.w); c7 += bf_hi(vB.w);
      }
    }
    // all-VALU butterfly over lane bits {0,1,3,5}
#define RED(x) x += dppmov<DPP_XOR1>(x); x += dppmov<DPP_XOR2>(x); \
               x += dppmov<DPP_ROR8>(x); x = sumxor32(x);
    RED(a0) RED(a1) RED(a2) RED(a3) RED(a4) RED(a5) RED(a6) RED(a7)
    RED(c0) RED(c1) RED(c2) RED(c3) RED(c4) RED(c5) RED(c6) RED(c7)
#undef RED

    // deposit z (every lane has full sums for its ch): dims [8ch..8ch+7]
    if (sl == 0) {
      float4 za0 = {a0, a1, a2, a3};
      float4 za1 = {a4, a5, a6, a7};
      *(float4*)&zsA[w][ch * 8]     = za0;
      *(float4*)&zsA[w][ch * 8 + 4] = za1;
    }
    if (sl == 1) {
      float4 zc0 = {c0, c1, c2, c3};
      float4 zc1 = {c4, c5, c6, c7};
      *(float4*)&zsB[w][ch * 8]     = zc0;
      *(float4*)&zsB[w][ch * 8 + 4] = zc1;
    }

    // ---- MLP node0 ----
    float tp = half ? 0.f : vb1;
    {
      const float4* zp = (const float4*)&zsA[w][half * 16];
      float4 q0 = zp[0], q1 = zp[1], q2 = zp[2], q3 = zp[3];
      tp = fmaf(q0.x, wr1[0], tp);  tp = fmaf(q0.y, wr1[1], tp);
      tp = fmaf(q0.z, wr1[2], tp);  tp = fmaf(q0.w, wr1[3], tp);
      tp = fmaf(q1.x, wr1[4], tp);  tp = fmaf(q1.y, wr1[5], tp);
      tp = fmaf(q1.z, wr1[6], tp);  tp = fmaf(q1.w, wr1[7], tp);
      tp = fmaf(q2.x, wr1[8], tp);  tp = fmaf(q2.y, wr1[9], tp);
      tp = fmaf(q2.z, wr1[10], tp); tp = fmaf(q2.w, wr1[11], tp);
      tp = fmaf(q3.x, wr1[12], tp); tp = fmaf(q3.y, wr1[13], tp);
      tp = fmaf(q3.z, wr1[14], tp); tp = fmaf(q3.w, wr1[15], tp);
    }
    tp = sumxor32(tp);
    tp = fmaxf(tp, 0.f);
    if (!half) tsA[w][j] = tp;

    float op = half ? 0.f : vb2;
    {
      const float4* tpp = (const float4*)&tsA[w][half * 16];
      float4 q0 = tpp[0], q1 = tpp[1], q2 = tpp[2], q3 = tpp[3];
      op = fmaf(q0.x, wr2[0], op);  op = fmaf(q0.y, wr2[1], op);
      op = fmaf(q0.z, wr2[2], op);  op = fmaf(q0.w, wr2[3], op);
      op = fmaf(q1.x, wr2[4], op);  op = fmaf(q1.y, wr2[5], op);
      op = fmaf(q1.z, wr2[6], op);  op = fmaf(q1.w, wr2[7], op);
      op = fmaf(q2.x, wr2[8], op);  op = fmaf(q2.y, wr2[9], op);
      op = fmaf(q2.z, wr2[10], op); op = fmaf(q2.w, wr2[11], op);
      op = fmaf(q3.x, wr2[12], op); op = fmaf(q3.y, wr2[13], op);
      op = fmaf(q3.z, wr2[14], op); op = fmaf(q3.w, wr2[15], op);
    }
    op = sumxor32(op);
    op = fmaxf(op, 0.f) * sc + sh;  // all lanes (value identical across halves)
    {
      float hi = dppmov<DPP_HI>(op);  // lane gets lane|1's value (VALU)
      if (!half && (j & 1) == 0) {
        unsigned pk = bf16_rne(op) | (bf16_rne(hi) << 16);
        ((unsigned*)hout16)[n0 * 16 + (j >> 1)] = pk;
      }
    }

    // ---- MLP node1 ----
    float tq = half ? 0.f : vb1;
    {
      const float4* zp = (const float4*)&zsB[w][half * 16];
      float4 q0 = zp[0], q1 = zp[1], q2 = zp[2], q3 = zp[3];
      tq = fmaf(q0.x, wr1[0], tq);  tq = fmaf(q0.y, wr1[1], tq);
      tq = fmaf(q0.z, wr1[2], tq);  tq = fmaf(q0.w, wr1[3], tq);
      tq = fmaf(q1.x, wr1[4], tq);  tq = fmaf(q1.y, wr1[5], tq);
      tq = fmaf(q1.z, wr1[6], tq);  tq = fmaf(q1.w, wr1[7], tq);
      tq = fmaf(q2.x, wr1[8], tq);  tq = fmaf(q2.y, wr1[9], tq);
      tq = fmaf(q2.z, wr1[10], tq); tq = fmaf(q2.w, wr1[11], tq);
      tq = fmaf(q3.x, wr1[12], tq); tq = fmaf(q3.y, wr1[13], tq);
      tq = fmaf(q3.z, wr1[14], tq); tq = fmaf(q3.w, wr1[15], tq);
    }
    tq = sumxor32(tq);
    tq = fmaxf(tq, 0.f);
    if (!half) tsB[w][j] = tq;

    float oq = half ? 0.f : vb2;
    {
      const float4* tpp = (const float4*)&tsB[w][half * 16];
      float4 q0 = tpp[0], q1 = tpp[1], q2 = tpp[2], q3 = tpp[3];
      oq = fmaf(q0.x, wr2[0], oq);  oq = fmaf(q0.y, wr2[1], oq);
      oq = fmaf(q0.z, wr2[2], oq);  oq = fmaf(q0.w, wr2[3], oq);
      oq = fmaf(q1.x, wr2[4], oq);  oq = fmaf(q1.y, wr2[5], oq);
      oq = fmaf(q1.z, wr2[6], oq);  oq = fmaf(q1.w, wr2[7], oq);
      oq = fmaf(q2.x, wr2[8], oq);  oq = fmaf(q2.y, wr2[9], oq);
      oq = fmaf(q2.z, wr2[10], oq); oq = fmaf(q2.w, wr2[11], oq);
      oq = fmaf(q3.x, wr2[12], oq); oq = fmaf(q3.y, wr2[13], oq);
      oq = fmaf(q3.z, wr2[14], oq); oq = fmaf(q3.w, wr2[15], oq);
    }
    oq = sumxor32(oq);
    oq = fmaxf(oq, 0.f) * sc + sh;
    {
      float hi = dppmov<DPP_HI>(oq);
      if (!half && (j & 1) == 0) {
        unsigned pk = bf16_rne(oq) | (bf16_rne(hi) << 16);
        ((unsigned*)hout16)[n1 * 16 + (j >> 1)] = pk;
      }
    }
  }
}

// ---------------- pool: one block per graph (batch sorted), bf16 in ----------------
__global__ __launch_bounds__(256) void pool_kernel(const unsigned short* __restrict__ h16,
                                                   const int* __restrict__ batch,
                                                   float* __restrict__ g) {
  __shared__ int s_lo, s_hi;
  __shared__ float red[8][33];
  int gr = blockIdx.x;
  if (threadIdx.x == 0) {
    int lo = 0, hi = N_NODES;
    while (lo < hi) { int m = (lo + hi) >> 1; if (batch[m] < gr) lo = m + 1; else hi = m; }
    s_lo = lo;
  } else if (threadIdx.x == 1) {
    int lo = 0, hi = N_NODES;
    while (lo < hi) { int m = (lo + hi) >> 1; if (batch[m] < gr + 1) lo = m + 1; else hi = m; }
    s_hi = lo;
  }
  __syncthreads();
  int lo = s_lo, hi = s_hi;
  int j = threadIdx.x & 31;
  int nd = threadIdx.x >> 5;
  float acc = 0.f;
  for (int n = lo + nd; n < hi; n += 8)
    acc += __uint_as_float((unsigned)h16[n * 32 + j] << 16);
  red[nd][j] = acc;
  __syncthreads();
  if (threadIdx.x < 32) {
    float s = 0.f;
#pragma unroll
    for (int r = 0; r < 8; ++r) s += red[r][j];
    g[gr * 32 + j] = s;
  }
}

// ---------------- head (fp32) ----------------
__global__ __launch_bounds__(256) void head_kernel(
    const float* __restrict__ g, const float* __restrict__ W1, const float* __restrict__ b1,
    const float* __restrict__ W2, const float* __restrict__ b2, float* __restrict__ out) {
  __shared__ float sW1[1024], sb1[32];
  __shared__ float sW2[64], sb2[2];
  __shared__ float zb[8][33], tb[8][33], lb[8][2];
  int tid = threadIdx.x;
  for (int i = tid; i < 1024; i += 256) sW1[i] = W1[i];
  if (tid < 64) sW2[tid] = W2[tid];
  if (tid < 32) sb1[tid] = b1[tid];
  if (tid < 2) sb2[tid] = b2[tid];
  int nd = tid >> 5;
  int gr = blockIdx.x * 8 + nd;
  int j = tid & 31;
  __syncthreads();
  float z = (gr < N_GRAPHS) ? g[gr * 32 + j] : 0.f;
  zb[nd][j] = z;
  __syncthreads();
  float t = sb1[j];
#pragma unroll
  for (int k = 0; k < 32; ++k) t = fmaf(zb[nd][k], sW1[k * 32 + j], t);
  t = fmaxf(t, 0.f);
  tb[nd][j] = t;
  __syncthreads();
  if (j < 2) {
    float l = sb2[j];
#pragma unroll
    for (int k = 0; k < 32; ++k) l = fmaf(tb[nd][k], sW2[k * 2 + j], l);
    lb[nd][j] = l;
  }
  __syncthreads();
  if (gr < N_GRAPHS && j < 2) {
    float l0 = lb[nd][0], l1 = lb[nd][1];
    float m = fmaxf(l0, l1);
    float lse = m + logf(expf(l0 - m) + expf(l1 - m));
    out[gr * 2 + j] = lb[nd][j] - lse;
  }
}

extern "C" void kernel_launch(void* const* d_in, const int* in_sizes, int n_in,
                              void* d_out, int out_size, void* d_ws, size_t ws_size,
                              hipStream_t stream) {
  const float* x     = (const float*)d_in[0];
  const int*   eidx  = (const int*)d_in[1];
  const int*   batch = (const int*)d_in[2];
  const float* c1W1  = (const float*)d_in[3];
  const float* c1b1  = (const float*)d_in[4];
  const float* c1W2  = (const float*)d_in[5];
  const float* c1b2  = (const float*)d_in[6];
  const float* csW1  = (const float*)d_in[7];
  const float* csb1  = (const float*)d_in[8];
  const float* csW2  = (const float*)d_in[9];
  const float* csb2  = (const float*)d_in[10];
  const float* bng   = (const float*)d_in[11];
  const float* bnb   = (const float*)d_in[12];
  const float* bnm   = (const float*)d_in[13];
  const float* bnv   = (const float*)d_in[14];
  const float* fc1W  = (const float*)d_in[15];
  const float* fc1b  = (const float*)d_in[16];
  const float* fc2W  = (const float*)d_in[17];
  const float* fc2b  = (const float*)d_in[18];
  float* out = (float*)d_out;

  const int* src = eidx;
  const int* dst = eidx + N_EDGES;

  // workspace (~50.2 MB)
  char* p = (char*)d_ws;
  unsigned short* hA16 = (unsigned short*)p; p += (size_t)N_NODES * 32 * 2;   // 6.4 MB
  unsigned short* hB16 = (unsigned short*)p; p += (size_t)N_NODES * 32 * 2;   // 6.4 MB
  int*      cnt  = (int*)p;      p += (size_t)N_NODES * 4;                    // 0.4 MB
  int*      csr  = (int*)p;      p += (size_t)NBKT * 128 * MAXDEG * 4;        // 25.6 MB
  unsigned* ebuf = (unsigned*)p; p += (size_t)NBKT * BCAP * 4;                // 11.2 MB
  int*      gCur = (int*)p;      p += 1024 * 4;
  float*    g    = (float*)p;    p += (size_t)N_GRAPHS * 32 * 4;
  // xc (bf16 [N,8], 1.6 MB) aliases ebuf: ebuf is dead after b2_csr completes
  unsigned* xc = ebuf;

  // ---- build: bucket pass + per-bucket padded-CSR pass ----
  (void)hipMemsetAsync(gCur, 0, 1024 * 4, stream);
  b1_bucket<<<(N_EDGES + E_PER_BLK - 1) / E_PER_BLK, 1024, 0, stream>>>(src, dst, gCur, ebuf);
  b2_csr<<<NBKT, 512, 0, stream>>>(ebuf, gCur, cnt, csr);

  // ---- x -> bf16 padded rows (after b2: xc aliases ebuf) ----
  xcvt_kernel<<<(N_NODES * 4 + 255) / 256, 256, 0, stream>>>(x, xc);

  // ---- conv1 (7->32) + relu + bn0 ----
  gin1<<<2048, 256, 0, stream>>>(
      (const unsigned short*)xc, cnt, csr, c1W1, c1b1, c1W2, c1b2,
      bng, bnb, bnm, bnv, hA16);

  // ---- conv2..5 (32->32) + relu + bn1..4 ----
  unsigned short* cur = hA16;
  unsigned short* nxt = hB16;
  for (int i = 0; i < 4; ++i) {
    gin_layer32<<<2048, 256, 0, stream>>>(
        cur, cnt, csr,
        csW1 + (size_t)i * 1024, csb1 + (size_t)i * 32,
        csW2 + (size_t)i * 1024, csb2 + (size_t)i * 32,
        bng + (size_t)(i + 1) * 32, bnb + (size_t)(i + 1) * 32,
        bnm + (size_t)(i + 1) * 32, bnv + (size_t)(i + 1) * 32, nxt);
    unsigned short* tmp = cur; cur = nxt; nxt = tmp;
  }

  pool_kernel<<<N_GRAPHS, 256, 0, stream>>>(cur, batch, g);
  head_kernel<<<(N_GRAPHS + 7) / 8, 256, 0, stream>>>(g, fc1W, fc1b, fc2W, fc2b, out);
}

// Round 8
// 358.586 us; speedup vs baseline: 1.1355x; 1.1355x over previous
//
#include <hip/hip_runtime.h>

#define N_NODES  100000
#define N_EDGES  2000000
#define N_GRAPHS 1000
#define NFEAT    7
#define BN_EPS   1e-5f
#define MAXDEG   64    // in-degree ~ Poisson(20); P(max over 100k > 63) < 1e-9

#define BSH      7     // 128-node dst buckets
#define NBKT     782   // ceil(100000/128)
#define BCAP     3584  // per-bucket edge cap: mean 2560 + 20 sigma
#define E_PER_BLK 4096

// bf16 helpers (storage only; all arithmetic fp32)
__device__ __forceinline__ unsigned bf16_rne(float f) {
  unsigned u = __float_as_uint(f);
  return (u + 0x7FFFu + ((u >> 16) & 1u)) >> 16;
}
__device__ __forceinline__ float bf_lo(unsigned u) { return __uint_as_float(u << 16); }
__device__ __forceinline__ float bf_hi(unsigned u) { return __uint_as_float(u & 0xFFFF0000u); }

// ---------------- b1: bucket edges by dst>>7, block-contiguous writes ----------------
__global__ __launch_bounds__(1024) void b1_bucket(const int* __restrict__ src,
                                                  const int* __restrict__ dst,
                                                  int* __restrict__ gCur,
                                                  unsigned* __restrict__ ebuf) {
  __shared__ int hist[NBKT], base[NBKT];
  int tid = threadIdx.x;
  for (int i = tid; i < NBKT; i += 1024) hist[i] = 0;
  __syncthreads();
  unsigned pk[4];
  int bo[4];
  int e0 = blockIdx.x * E_PER_BLK;
#pragma unroll
  for (int k = 0; k < 4; ++k) {
    int e = e0 + k * 1024 + tid;
    if (e < N_EDGES) {
      int d = dst[e], s = src[e];
      int b = d >> BSH;
      int off = atomicAdd(&hist[b], 1);
      pk[k] = ((unsigned)(d & 127) << 17) | (unsigned)s;
      bo[k] = (b << 17) | off;
    } else {
      bo[k] = -1;
    }
  }
  __syncthreads();
  for (int i = tid; i < NBKT; i += 1024)
    base[i] = hist[i] ? atomicAdd(&gCur[i], hist[i]) : 0;
  __syncthreads();
#pragma unroll
  for (int k = 0; k < 4; ++k) {
    if (bo[k] >= 0) {
      int b = bo[k] >> 17, off = bo[k] & 0x1FFFF;
      int p = base[b] + off;
      if (p < BCAP) ebuf[(size_t)b * BCAP + p] = pk[k];
    }
  }
}

// ---------------- b2: one block per bucket -> padded csr + cnt ----------------
__global__ __launch_bounds__(512) void b2_csr(const unsigned* __restrict__ ebuf,
                                              const int* __restrict__ gCnt,
                                              int* __restrict__ cnt,
                                              int* __restrict__ csr) {
  __shared__ int hist[128];
  __shared__ int stage[128 * MAXDEG];
  int b = blockIdx.x, tid = threadIdx.x;
  if (tid < 128) hist[tid] = 0;
  __syncthreads();
  int n = gCnt[b];
  if (n > BCAP) n = BCAP;
  const unsigned* eb = ebuf + (size_t)b * BCAP;
  for (int i = tid; i < n; i += 512) {
    unsigned pk = eb[i];
    int dloc = (int)(pk >> 17);
    int slot = atomicAdd(&hist[dloc], 1);
    if (slot < MAXDEG) stage[(dloc << 6) + slot] = (int)(pk & 0x1FFFFu);
  }
  __syncthreads();
  if (tid < 128) {
    int gnode = (b << BSH) + tid;
    if (gnode < N_NODES) cnt[gnode] = hist[tid];
  }
  const int4* st4 = (const int4*)stage;
  int4* dst4 = (int4*)(csr + (size_t)b * (128 * MAXDEG));
  for (int i = tid; i < 128 * MAXDEG / 4; i += 512) dst4[i] = st4[i];
}

// ---------------- xcvt: x (fp32 [N,7]) -> xc (bf16 [N,8], pad dim7 = 0) ----------------
__global__ __launch_bounds__(256) void xcvt_kernel(const float* __restrict__ x,
                                                   unsigned* __restrict__ xc) {
  int i = blockIdx.x * 256 + threadIdx.x;
  if (i >= N_NODES * 4) return;
  int n = i >> 2, p = i & 3;
  float lo = x[n * 7 + 2 * p];
  float hi = (2 * p + 1 < 7) ? x[n * 7 + 2 * p + 1] : 0.f;
  xc[i] = bf16_rne(lo) | (bf16_rne(hi) << 16);
}

// ---------------- conv1: node-PAIR cooperative-row gather (proven R1/R2) ----------------
__global__ __launch_bounds__(256) void gin1(
    const unsigned short* __restrict__ xc16, const int* __restrict__ cnt,
    const int* __restrict__ csr,
    const float* __restrict__ W1, const float* __restrict__ b1,
    const float* __restrict__ W2, const float* __restrict__ b2,
    const float* __restrict__ gamma, const float* __restrict__ beta,
    const float* __restrict__ mean, const float* __restrict__ var,
    unsigned short* __restrict__ hout16) {
  __shared__ __align__(16) float zsA[4][8], zsB[4][8];
  __shared__ __align__(16) float tsA[4][32], tsB[4][32];
  int tid = threadIdx.x;
  int w = __builtin_amdgcn_readfirstlane(tid >> 6);
  int lane = tid & 63;
  int grp = lane >> 2;   // row group (16 rows per gather step)
  int ch  = lane & 3;    // 4-byte chunk = dims [2ch, 2ch+1]
  int half = lane >> 5, j = lane & 31;  // MLP roles

  float wr1[4], wr2[16];
#pragma unroll
  for (int i = 0; i < 4; ++i) {
    int k = half * 4 + i;
    wr1[i] = (k < 7) ? W1[k * 32 + j] : 0.f;
  }
#pragma unroll
  for (int i = 0; i < 16; ++i) wr2[i] = W2[(half * 16 + i) * 32 + j];
  float vb1 = b1[j], vb2 = b2[j];
  float sc = gamma[j] * rsqrtf(var[j] + BN_EPS);
  float sh = beta[j] - mean[j] * sc;

  const unsigned* xc32 = (const unsigned*)xc16;  // 4 x unsigned per 16-B row

  const int NW = gridDim.x * 4;
  const int NPAIR = N_NODES / 2;
  for (int pr = blockIdx.x * 4 + w; pr < NPAIR; pr += NW) {
    int n0 = 2 * pr, n1 = n0 + 1;
    int d0 = cnt[n0];
    int d1 = cnt[n1];
    if (d0 > 63) d0 = 63;
    if (d1 > 63) d1 = 63;
    int dE0 = d0 + 1, dE1 = d1 + 1;

    int idx0 = (lane < d0) ? csr[n0 * MAXDEG + lane] : n0;
    int idx1 = (lane < d1) ? csr[n1 * MAXDEG + lane] : n1;

    unsigned vA[4], vB[4];
#pragma unroll
    for (int s = 0; s < 4; ++s) {
      int sidA = __shfl(idx0, s * 16 + grp);
      vA[s] = xc32[(size_t)sidA * 4 + ch];
    }
#pragma unroll
    for (int s = 0; s < 4; ++s) {
      int sidB = __shfl(idx1, s * 16 + grp);
      vB[s] = xc32[(size_t)sidB * 4 + ch];
    }

    float a0 = 0.f, a1 = 0.f;   // node0
    float c0 = 0.f, c1 = 0.f;   // node1
#pragma unroll
    for (int s = 0; s < 4; ++s) {
      int e = s * 16 + grp;
      if (e < dE0) { a0 += bf_lo(vA[s]); a1 += bf_hi(vA[s]); }
      if (e < dE1) { c0 += bf_lo(vB[s]); c1 += bf_hi(vB[s]); }
    }
#pragma unroll
    for (int m = 4; m <= 32; m <<= 1) {
      a0 += __shfl_xor(a0, m); a1 += __shfl_xor(a1, m);
      c0 += __shfl_xor(c0, m); c1 += __shfl_xor(c1, m);
    }
    if (grp == 0) {  // lanes 0..3 deposit dims [2ch, 2ch+1]
      float2 za = {a0, a1};
      float2 zc = {c0, c1};
      *(float2*)&zsA[w][ch * 2] = za;
      *(float2*)&zsB[w][ch * 2] = zc;
    }

    // ---- MLP node0 ----
    float tp = half ? 0.f : vb1;
    {
      const float4* zp = (const float4*)&zsA[w][half * 4];
      float4 z0 = zp[0];
      tp = fmaf(z0.x, wr1[0], tp); tp = fmaf(z0.y, wr1[1], tp);
      tp = fmaf(z0.z, wr1[2], tp); tp = fmaf(z0.w, wr1[3], tp);
    }
    tp += __shfl_xor(tp, 32);
    tp = fmaxf(tp, 0.f);
    if (!half) tsA[w][j] = tp;

    float op = half ? 0.f : vb2;
    {
      const float4* tpp = (const float4*)&tsA[w][half * 16];
      float4 t0 = tpp[0], t1 = tpp[1], t2 = tpp[2], t3 = tpp[3];
      op = fmaf(t0.x, wr2[0], op);  op = fmaf(t0.y, wr2[1], op);
      op = fmaf(t0.z, wr2[2], op);  op = fmaf(t0.w, wr2[3], op);
      op = fmaf(t1.x, wr2[4], op);  op = fmaf(t1.y, wr2[5], op);
      op = fmaf(t1.z, wr2[6], op);  op = fmaf(t1.w, wr2[7], op);
      op = fmaf(t2.x, wr2[8], op);  op = fmaf(t2.y, wr2[9], op);
      op = fmaf(t2.z, wr2[10], op); op = fmaf(t2.w, wr2[11], op);
      op = fmaf(t3.x, wr2[12], op); op = fmaf(t3.y, wr2[13], op);
      op = fmaf(t3.z, wr2[14], op); op = fmaf(t3.w, wr2[15], op);
    }
    op += __shfl_xor(op, 32);
    if (!half) {
      op = fmaxf(op, 0.f) * sc + sh;
      float hi = __shfl(op, j | 1);
      if ((j & 1) == 0) {
        unsigned pk = bf16_rne(op) | (bf16_rne(hi) << 16);
        ((unsigned*)hout16)[n0 * 16 + (j >> 1)] = pk;
      }
    }

    // ---- MLP node1 ----
    float tq = half ? 0.f : vb1;
    {
      const float4* zp = (const float4*)&zsB[w][half * 4];
      float4 z0 = zp[0];
      tq = fmaf(z0.x, wr1[0], tq); tq = fmaf(z0.y, wr1[1], tq);
      tq = fmaf(z0.z, wr1[2], tq); tq = fmaf(z0.w, wr1[3], tq);
    }
    tq += __shfl_xor(tq, 32);
    tq = fmaxf(tq, 0.f);
    if (!half) tsB[w][j] = tq;

    float oq = half ? 0.f : vb2;
    {
      const float4* tpp = (const float4*)&tsB[w][half * 16];
      float4 t0 = tpp[0], t1 = tpp[1], t2 = tpp[2], t3 = tpp[3];
      oq = fmaf(t0.x, wr2[0], oq);  oq = fmaf(t0.y, wr2[1], oq);
      oq = fmaf(t0.z, wr2[2], oq);  oq = fmaf(t0.w, wr2[3], oq);
      oq = fmaf(t1.x, wr2[4], oq);  oq = fmaf(t1.y, wr2[5], oq);
      oq = fmaf(t1.z, wr2[6], oq);  oq = fmaf(t1.w, wr2[7], oq);
      oq = fmaf(t2.x, wr2[8], oq);  oq = fmaf(t2.y, wr2[9], oq);
      oq = fmaf(t2.z, wr2[10], oq); oq = fmaf(t2.w, wr2[11], oq);
      oq = fmaf(t3.x, wr2[12], oq); oq = fmaf(t3.y, wr2[13], oq);
      oq = fmaf(t3.z, wr2[14], oq); oq = fmaf(t3.w, wr2[15], oq);
    }
    oq += __shfl_xor(oq, 32);
    if (!half) {
      oq = fmaxf(oq, 0.f) * sc + sh;
      float hi = __shfl(oq, j | 1);
      if ((j & 1) == 0) {
        unsigned pk = bf16_rne(oq) | (bf16_rne(hi) << 16);
        ((unsigned*)hout16)[n1 * 16 + (j >> 1)] = pk;
      }
    }
  }
}

// ---------------- conv2..5: pair gather + NEXT-pair P-stage prefetch (R7b) ----------------
// Body identical to the proven R1 kernel; the only change is that the next
// pair's cnt+csr loads are issued at the top of the iteration, overlapping
// their latency with the current pair's gather + compute.
__global__ __launch_bounds__(256) void gin_layer32(
    const unsigned short* __restrict__ hin16, const int* __restrict__ cnt,
    const int* __restrict__ csr,
    const float* __restrict__ W1, const float* __restrict__ b1,
    const float* __restrict__ W2, const float* __restrict__ b2,
    const float* __restrict__ gamma, const float* __restrict__ beta,
    const float* __restrict__ mean, const float* __restrict__ var,
    unsigned short* __restrict__ hout16) {
  __shared__ __align__(16) float zsA[4][32], tsA[4][32];
  __shared__ __align__(16) float zsB[4][32], tsB[4][32];
  int tid = threadIdx.x;
  int w = __builtin_amdgcn_readfirstlane(tid >> 6);  // wave id, force-scalar
  int lane = tid & 63;
  int grp = lane >> 3;   // row group within a gather step
  int ch  = lane & 7;    // 8-byte chunk = dims [4ch, 4ch+3]
  int half = lane >> 5, j = lane & 31;  // MLP roles

  float wr1[16], wr2[16];
#pragma unroll
  for (int i = 0; i < 16; ++i) wr1[i] = W1[(half * 16 + i) * 32 + j];
#pragma unroll
  for (int i = 0; i < 16; ++i) wr2[i] = W2[(half * 16 + i) * 32 + j];
  float vb1 = b1[j], vb2 = b2[j];
  float sc = gamma[j] * rsqrtf(var[j] + BN_EPS);
  float sh = beta[j] - mean[j] * sc;

  const int NW = gridDim.x * 4;
  const int NPAIR = N_NODES / 2;  // 50000

  // prologue: P-stage for the first pair (pr < 8192 < NPAIR always)
  int pr = blockIdx.x * 4 + w;
  int n0 = 2 * pr, n1 = n0 + 1;
  int d0 = cnt[n0];
  int d1 = cnt[n1];
  if (d0 > 63) d0 = 63;
  if (d1 > 63) d1 = 63;
  int idx0 = (lane < d0) ? csr[n0 * MAXDEG + lane] : n0;
  int idx1 = (lane < d1) ? csr[n1 * MAXDEG + lane] : n1;

  while (true) {
    // ---- prefetch next pair's P-stage (hidden behind this pair's work) ----
    int prn = pr + NW;
    bool hasN = prn < NPAIR;
    int d0n = 0, d1n = 0, i0n = 0, i1n = 0;
    if (hasN) {
      int m0 = 2 * prn, m1 = m0 + 1;
      d0n = cnt[m0];
      d1n = cnt[m1];
      if (d0n > 63) d0n = 63;
      if (d1n > 63) d1n = 63;
      i0n = (lane < d0n) ? csr[m0 * MAXDEG + lane] : m0;
      i1n = (lane < d1n) ? csr[m1 * MAXDEG + lane] : m1;
    }

    int dE0 = d0 + 1, dE1 = d1 + 1;  // + self rows

    // ---- batched gather: issue all 16 loads, then accumulate with guards ----
    uint2 vA[8], vB[8];
#pragma unroll
    for (int s = 0; s < 8; ++s) {
      int sidA = __shfl(idx0, s * 8 + grp);
      vA[s] = *(const uint2*)(hin16 + (size_t)sidA * 32 + ch * 4);
    }
#pragma unroll
    for (int s = 0; s < 8; ++s) {
      int sidB = __shfl(idx1, s * 8 + grp);
      vB[s] = *(const uint2*)(hin16 + (size_t)sidB * 32 + ch * 4);
    }

    float a0 = 0.f, a1 = 0.f, a2 = 0.f, a3 = 0.f;   // node0
    float c0 = 0.f, c1 = 0.f, c2 = 0.f, c3 = 0.f;   // node1
#pragma unroll
    for (int s = 0; s < 8; ++s) {
      int e = s * 8 + grp;
      if (e < dE0) {
        a0 += bf_lo(vA[s].x); a1 += bf_hi(vA[s].x);
        a2 += bf_lo(vA[s].y); a3 += bf_hi(vA[s].y);
      }
      if (e < dE1) {
        c0 += bf_lo(vB[s].x); c1 += bf_hi(vB[s].x);
        c2 += bf_lo(vB[s].y); c3 += bf_hi(vB[s].y);
      }
    }
#pragma unroll
    for (int m = 8; m <= 32; m <<= 1) {
      a0 += __shfl_xor(a0, m); a1 += __shfl_xor(a1, m);
      a2 += __shfl_xor(a2, m); a3 += __shfl_xor(a3, m);
      c0 += __shfl_xor(c0, m); c1 += __shfl_xor(c1, m);
      c2 += __shfl_xor(c2, m); c3 += __shfl_xor(c3, m);
    }
    if (grp == 0) {
      float4 za = {a0, a1, a2, a3};
      float4 zc = {c0, c1, c2, c3};
      *(float4*)&zsA[w][ch * 4] = za;
      *(float4*)&zsB[w][ch * 4] = zc;
    }

    // ---- MLP node0 ----
    float tp = half ? 0.f : vb1;
    {
      const float4* zp = (const float4*)&zsA[w][half * 16];
      float4 q0 = zp[0], q1 = zp[1], q2 = zp[2], q3 = zp[3];
      tp = fmaf(q0.x, wr1[0], tp);  tp = fmaf(q0.y, wr1[1], tp);
      tp = fmaf(q0.z, wr1[2], tp);  tp = fmaf(q0.w, wr1[3], tp);
      tp = fmaf(q1.x, wr1[4], tp);  tp = fmaf(q1.y, wr1[5], tp);
      tp = fmaf(q1.z, wr1[6], tp);  tp = fmaf(q1.w, wr1[7], tp);
      tp = fmaf(q2.x, wr1[8], tp);  tp = fmaf(q2.y, wr1[9], tp);
      tp = fmaf(q2.z, wr1[10], tp); tp = fmaf(q2.w, wr1[11], tp);
      tp = fmaf(q3.x, wr1[12], tp); tp = fmaf(q3.y, wr1[13], tp);
      tp = fmaf(q3.z, wr1[14], tp); tp = fmaf(q3.w, wr1[15], tp);
    }
    tp += __shfl_xor(tp, 32);
    tp = fmaxf(tp, 0.f);
    if (!half) tsA[w][j] = tp;

    float op = half ? 0.f : vb2;
    {
      const float4* tpp = (const float4*)&tsA[w][half * 16];
      float4 q0 = tpp[0], q1 = tpp[1], q2 = tpp[2], q3 = tpp[3];
      op = fmaf(q0.x, wr2[0], op);  op = fmaf(q0.y, wr2[1], op);
      op = fmaf(q0.z, wr2[2], op);  op = fmaf(q0.w, wr2[3], op);
      op = fmaf(q1.x, wr2[4], op);  op = fmaf(q1.y, wr2[5], op);
      op = fmaf(q1.z, wr2[6], op);  op = fmaf(q1.w, wr2[7], op);
      op = fmaf(q2.x, wr2[8], op);  op = fmaf(q2.y, wr2[9], op);
      op = fmaf(q2.z, wr2[10], op); op = fmaf(q2.w, wr2[11], op);
      op = fmaf(q3.x, wr2[12], op); op = fmaf(q3.y, wr2[13], op);
      op = fmaf(q3.z, wr2[14], op); op = fmaf(q3.w, wr2[15], op);
    }
    op += __shfl_xor(op, 32);
    if (!half) {
      op = fmaxf(op, 0.f) * sc + sh;
      float hi = __shfl(op, j | 1);
      if ((j & 1) == 0) {
        unsigned pk = bf16_rne(op) | (bf16_rne(hi) << 16);
        ((unsigned*)hout16)[n0 * 16 + (j >> 1)] = pk;
      }
    }

    // ---- MLP node1 ----
    float tq = half ? 0.f : vb1;
    {
      const float4* zp = (const float4*)&zsB[w][half * 16];
      float4 q0 = zp[0], q1 = zp[1], q2 = zp[2], q3 = zp[3];
      tq = fmaf(q0.x, wr1[0], tq);  tq = fmaf(q0.y, wr1[1], tq);
      tq = fmaf(q0.z, wr1[2], tq);  tq = fmaf(q0.w, wr1[3], tq);
      tq = fmaf(q1.x, wr1[4], tq);  tq = fmaf(q1.y, wr1[5], tq);
      tq = fmaf(q1.z, wr1[6], tq);  tq = fmaf(q1.w, wr1[7], tq);
      tq = fmaf(q2.x, wr1[8], tq);  tq = fmaf(q2.y, wr1[9], tq);
      tq = fmaf(q2.z, wr1[10], tq); tq = fmaf(q2.w, wr1[11], tq);
      tq = fmaf(q3.x, wr1[12], tq); tq = fmaf(q3.y, wr1[13], tq);
      tq = fmaf(q3.z, wr1[14], tq); tq = fmaf(q3.w, wr1[15], tq);
    }
    tq += __shfl_xor(tq, 32);
    tq = fmaxf(tq, 0.f);
    if (!half) tsB[w][j] = tq;

    float oq = half ? 0.f : vb2;
    {
      const float4* tpp = (const float4*)&tsB[w][half * 16];
      float4 q0 = tpp[0], q1 = tpp[1], q2 = tpp[2], q3 = tpp[3];
      oq = fmaf(q0.x, wr2[0], oq);  oq = fmaf(q0.y, wr2[1], oq);
      oq = fmaf(q0.z, wr2[2], oq);  oq = fmaf(q0.w, wr2[3], oq);
      oq = fmaf(q1.x, wr2[4], oq);  oq = fmaf(q1.y, wr2[5], oq);
      oq = fmaf(q1.z, wr2[6], oq);  oq = fmaf(q1.w, wr2[7], oq);
      oq = fmaf(q2.x, wr2[8], oq);  oq = fmaf(q2.y, wr2[9], oq);
      oq = fmaf(q2.z, wr2[10], oq); oq = fmaf(q2.w, wr2[11], oq);
      oq = fmaf(q3.x, wr2[12], oq); oq = fmaf(q3.y, wr2[13], oq);
      oq = fmaf(q3.z, wr2[14], oq); oq = fmaf(q3.w, wr2[15], oq);
    }
    oq += __shfl_xor(oq, 32);
    if (!half) {
      oq = fmaxf(oq, 0.f) * sc + sh;
      float hi = __shfl(oq, j | 1);
      if ((j & 1) == 0) {
        unsigned pk = bf16_rne(oq) | (bf16_rne(hi) << 16);
        ((unsigned*)hout16)[n1 * 16 + (j >> 1)] = pk;
      }
    }

    // ---- rotate prefetched state ----
    if (!hasN) break;
    pr = prn;
    n0 = 2 * pr; n1 = n0 + 1;
    d0 = d0n; d1 = d1n; idx0 = i0n; idx1 = i1n;
  }
}

// ---------------- pool: one block per graph (batch sorted), bf16 in ----------------
__global__ __launch_bounds__(256) void pool_kernel(const unsigned short* __restrict__ h16,
                                                   const int* __restrict__ batch,
                                                   float* __restrict__ g) {
  __shared__ int s_lo, s_hi;
  __shared__ float red[8][33];
  int gr = blockIdx.x;
  if (threadIdx.x == 0) {
    int lo = 0, hi = N_NODES;
    while (lo < hi) { int m = (lo + hi) >> 1; if (batch[m] < gr) lo = m + 1; else hi = m; }
    s_lo = lo;
  } else if (threadIdx.x == 1) {
    int lo = 0, hi = N_NODES;
    while (lo < hi) { int m = (lo + hi) >> 1; if (batch[m] < gr + 1) lo = m + 1; else hi = m; }
    s_hi = lo;
  }
  __syncthreads();
  int lo = s_lo, hi = s_hi;
  int j = threadIdx.x & 31;
  int nd = threadIdx.x >> 5;
  float acc = 0.f;
  for (int n = lo + nd; n < hi; n += 8)
    acc += __uint_as_float((unsigned)h16[n * 32 + j] << 16);
  red[nd][j] = acc;
  __syncthreads();
  if (threadIdx.x < 32) {
    float s = 0.f;
#pragma unroll
    for (int r = 0; r < 8; ++r) s += red[r][j];
    g[gr * 32 + j] = s;
  }
}

// ---------------- head (fp32) ----------------
__global__ __launch_bounds__(256) void head_kernel(
    const float* __restrict__ g, const float* __restrict__ W1, const float* __restrict__ b1,
    const float* __restrict__ W2, const float* __restrict__ b2, float* __restrict__ out) {
  __shared__ float sW1[1024], sb1[32];
  __shared__ float sW2[64], sb2[2];
  __shared__ float zb[8][33], tb[8][33], lb[8][2];
  int tid = threadIdx.x;
  for (int i = tid; i < 1024; i += 256) sW1[i] = W1[i];
  if (tid < 64) sW2[tid] = W2[tid];
  if (tid < 32) sb1[tid] = b1[tid];
  if (tid < 2) sb2[tid] = b2[tid];
  int nd = tid >> 5;
  int gr = blockIdx.x * 8 + nd;
  int j = tid & 31;
  __syncthreads();
  float z = (gr < N_GRAPHS) ? g[gr * 32 + j] : 0.f;
  zb[nd][j] = z;
  __syncthreads();
  float t = sb1[j];
#pragma unroll
  for (int k = 0; k < 32; ++k) t = fmaf(zb[nd][k], sW1[k * 32 + j], t);
  t = fmaxf(t, 0.f);
  tb[nd][j] = t;
  __syncthreads();
  if (j < 2) {
    float l = sb2[j];
#pragma unroll
    for (int k = 0; k < 32; ++k) l = fmaf(tb[nd][k], sW2[k * 2 + j], l);
    lb[nd][j] = l;
  }
  __syncthreads();
  if (gr < N_GRAPHS && j < 2) {
    float l0 = lb[nd][0], l1 = lb[nd][1];
    float m = fmaxf(l0, l1);
    float lse = m + logf(expf(l0 - m) + expf(l1 - m));
    out[gr * 2 + j] = lb[nd][j] - lse;
  }
}

extern "C" void kernel_launch(void* const* d_in, const int* in_sizes, int n_in,
                              void* d_out, int out_size, void* d_ws, size_t ws_size,
                              hipStream_t stream) {
  const float* x     = (const float*)d_in[0];
  const int*   eidx  = (const int*)d_in[1];
  const int*   batch = (const int*)d_in[2];
  const float* c1W1  = (const float*)d_in[3];
  const float* c1b1  = (const float*)d_in[4];
  const float* c1W2  = (const float*)d_in[5];
  const float* c1b2  = (const float*)d_in[6];
  const float* csW1  = (const float*)d_in[7];
  const float* csb1  = (const float*)d_in[8];
  const float* csW2  = (const float*)d_in[9];
  const float* csb2  = (const float*)d_in[10];
  const float* bng   = (const float*)d_in[11];
  const float* bnb   = (const float*)d_in[12];
  const float* bnm   = (const float*)d_in[13];
  const float* bnv   = (const float*)d_in[14];
  const float* fc1W  = (const float*)d_in[15];
  const float* fc1b  = (const float*)d_in[16];
  const float* fc2W  = (const float*)d_in[17];
  const float* fc2b  = (const float*)d_in[18];
  float* out = (float*)d_out;

  const int* src = eidx;
  const int* dst = eidx + N_EDGES;

  // workspace (~50.2 MB)
  char* p = (char*)d_ws;
  unsigned short* hA16 = (unsigned short*)p; p += (size_t)N_NODES * 32 * 2;   // 6.4 MB
  unsigned short* hB16 = (unsigned short*)p; p += (size_t)N_NODES * 32 * 2;   // 6.4 MB
  int*      cnt  = (int*)p;      p += (size_t)N_NODES * 4;                    // 0.4 MB
  int*      csr  = (int*)p;      p += (size_t)NBKT * 128 * MAXDEG * 4;        // 25.6 MB
  unsigned* ebuf = (unsigned*)p; p += (size_t)NBKT * BCAP * 4;                // 11.2 MB
  int*      gCur = (int*)p;      p += 1024 * 4;
  float*    g    = (float*)p;    p += (size_t)N_GRAPHS * 32 * 4;
  // xc (bf16 [N,8], 1.6 MB) aliases ebuf: ebuf is dead after b2_csr completes
  unsigned* xc = ebuf;

  // ---- build: bucket pass + per-bucket padded-CSR pass ----
  (void)hipMemsetAsync(gCur, 0, 1024 * 4, stream);
  b1_bucket<<<(N_EDGES + E_PER_BLK - 1) / E_PER_BLK, 1024, 0, stream>>>(src, dst, gCur, ebuf);
  b2_csr<<<NBKT, 512, 0, stream>>>(ebuf, gCur, cnt, csr);

  // ---- x -> bf16 padded rows (after b2: xc aliases ebuf) ----
  xcvt_kernel<<<(N_NODES * 4 + 255) / 256, 256, 0, stream>>>(x, xc);

  // ---- conv1 (7->32) + relu + bn0 ----
  gin1<<<2048, 256, 0, stream>>>(
      (const unsigned short*)xc, cnt, csr, c1W1, c1b1, c1W2, c1b2,
      bng, bnb, bnm, bnv, hA16);

  // ---- conv2..5 (32->32) + relu + bn1..4, with next-pair P-stage prefetch ----
  unsigned short* cur = hA16;
  unsigned short* nxt = hB16;
  for (int i = 0; i < 4; ++i) {
    gin_layer32<<<2048, 256, 0, stream>>>(
        cur, cnt, csr,
        csW1 + (size_t)i * 1024, csb1 + (size_t)i * 32,
        csW2 + (size_t)i * 1024, csb2 + (size_t)i * 32,
        bng + (size_t)(i + 1) * 32, bnb + (size_t)(i + 1) * 32,
        bnm + (size_t)(i + 1) * 32, bnv + (size_t)(i + 1) * 32, nxt);
    unsigned short* tmp = cur; cur = nxt; nxt = tmp;
  }

  pool_kernel<<<N_GRAPHS, 256, 0, stream>>>(cur, batch, g);
  head_kernel<<<(N_GRAPHS + 7) / 8, 256, 0, stream>>>(g, fc1W, fc1b, fc2W, fc2b, out);
}